// Round 1
// baseline (694.257 us; speedup 1.0000x reference)
//
#include <hip/hip_runtime.h>
#include <math.h>

#define HW 4096

// ---------------- K1: front 3x3 convs (x1_co = relu(conv40), x2_co = conv1) ----
__global__ __launch_bounds__(256) void k_front(
    const float* __restrict__ x, const float* __restrict__ y,
    const float* __restrict__ conv_w, const float* __restrict__ conv_b,
    const float* __restrict__ c132_w, const float* __restrict__ c132_b,
    float* __restrict__ x1, float* __restrict__ x2)
{
    int pix = blockIdx.x * 256 + threadIdx.x;
    int oc = blockIdx.y;
    int b  = blockIdx.z;
    int h = pix >> 6, w = pix & 63;

    bool hv[3] = {h > 0, true, h < 63};
    bool wv[3] = {w > 0, true, w < 63};
    int  hh[3] = {h - 1, h, h + 1};
    int  wwI[3] = {w - 1, w, w + 1};

    // y window
    const float* yb = y + b * HW;
    float yw[3][3];
    #pragma unroll
    for (int dy = 0; dy < 3; ++dy)
    #pragma unroll
    for (int dx = 0; dx < 3; ++dx)
        yw[dy][dx] = (hv[dy] && wv[dx]) ? yb[hh[dy] * 64 + wwI[dx]] : 0.f;

    float acc  = conv_b[oc];
    float acc2 = c132_b[oc];
    const float* wb = conv_w + oc * 40 * 9;
    const float* w2 = c132_w + oc * 9;

    // y contributions: every 5th input channel (k==4) of each group reads y
    #pragma unroll
    for (int t = 0; t < 9; ++t){
        float wy = 0.f;
        #pragma unroll
        for (int g = 0; g < 8; ++g) wy += wb[(5 * g + 4) * 9 + t];
        float yv = yw[t / 3][t % 3];
        acc  += wy * yv;
        acc2 += w2[t] * yv;
    }

    // x contributions
    const float* xb = x + b * 32 * HW;
    for (int ic = 0; ic < 32; ++ic){
        const float* xc = xb + ic * HW;
        const float* wc = wb + (5 * (ic >> 2) + (ic & 3)) * 9;
        #pragma unroll
        for (int dy = 0; dy < 3; ++dy)
        #pragma unroll
        for (int dx = 0; dx < 3; ++dx){
            float xv = (hv[dy] && wv[dx]) ? xc[hh[dy] * 64 + wwI[dx]] : 0.f;
            acc = fmaf(wc[dy * 3 + dx], xv, acc);
        }
    }
    int o = (b * 32 + oc) * HW + pix;
    x1[o] = acc > 0.f ? acc : 0.f;
    x2[o] = acc2;
}

// ---------------- K2: six 1x1 projections ------------------------------------
__global__ __launch_bounds__(256) void k_proj(
    const float* __restrict__ x1, const float* __restrict__ x2,
    const float* __restrict__ q1w, const float* __restrict__ q1b,
    const float* __restrict__ k1w, const float* __restrict__ k1b,
    const float* __restrict__ q2w, const float* __restrict__ q2b,
    const float* __restrict__ k2w, const float* __restrict__ k2b,
    const float* __restrict__ q3w, const float* __restrict__ q3b,
    const float* __restrict__ k3w, const float* __restrict__ k3b,
    float* __restrict__ Q1, float* __restrict__ K1,
    float* __restrict__ Q2, float* __restrict__ K2,
    float* __restrict__ YQ, float* __restrict__ YK)
{
    int tid = blockIdx.x * 256 + threadIdx.x;   // 0..32767
    int b = tid >> 12, m = tid & 4095;
    float v1[32], v2[32];
    const float* p1 = x1 + b * 32 * HW + m;
    const float* p2 = x2 + b * 32 * HW + m;
    #pragma unroll
    for (int c = 0; c < 32; ++c){ v1[c] = p1[c * HW]; v2[c] = p2[c * HW]; }

    for (int oc = 0; oc < 32; ++oc){
        float aq1 = q1b[oc], ak1 = k1b[oc], aq2 = q2b[oc];
        float ak2 = k2b[oc], aq3 = q3b[oc], ak3 = k3b[oc];
        #pragma unroll
        for (int c = 0; c < 32; ++c){
            float v = v1[c], u = v2[c];
            aq1 = fmaf(q1w[oc * 32 + c], v, aq1);
            ak1 = fmaf(k1w[oc * 32 + c], v, ak1);
            aq2 = fmaf(q2w[oc * 32 + c], v, aq2);
            ak2 = fmaf(k2w[oc * 32 + c], v, ak2);
            aq3 = fmaf(q3w[oc * 32 + c], u, aq3);
            ak3 = fmaf(k3w[oc * 32 + c], u, ak3);
        }
        int o = (b * 32 + oc) * HW + m;
        Q1[o] = aq1; K1[o] = ak1; Q2[o] = aq2;
        K2[o] = ak2; YQ[o] = aq3; YK[o] = ak3;
    }
}

// ---------------- K3: channel attention partial sums -------------------------
__global__ __launch_bounds__(256) void k_chan_part(
    const float* __restrict__ K1, const float* __restrict__ Q2,
    float* __restrict__ Scp)
{
    __shared__ float k1s[128 * 33];
    __shared__ float q2s[128 * 33];
    int chunk = blockIdx.x;     // 0..31, 128 n each
    int b = blockIdx.y;
    int n0 = chunk * 128;
    int t = threadIdx.x;
    for (int i = 0; i < 16; ++i){
        int idx = i * 256 + t;
        int c = idx >> 7, nl = idx & 127;
        k1s[nl * 33 + c] = K1[(b * 32 + c) * HW + n0 + nl];
        q2s[nl * 33 + c] = Q2[(b * 32 + c) * HW + n0 + nl];
    }
    __syncthreads();
    float acc[4] = {0.f, 0.f, 0.f, 0.f};
    int d = t & 31, c0 = t >> 5;
    for (int nl = 0; nl < 128; ++nl){
        float qv = q2s[nl * 33 + d];
        #pragma unroll
        for (int i = 0; i < 4; ++i)
            acc[i] = fmaf(k1s[nl * 33 + c0 + 8 * i], qv, acc[i]);
    }
    #pragma unroll
    for (int i = 0; i < 4; ++i)
        Scp[(b * 32 + chunk) * 1024 + (c0 + 8 * i) * 32 + d] = acc[i];
}

// ---------------- K4: channel softmax + fold conv6 W2 into M2 ----------------
__global__ __launch_bounds__(1024) void k_chan_fin(
    const float* __restrict__ Scp, const float* __restrict__ c6w,
    float* __restrict__ M2)
{
    __shared__ float pc[32 * 33];
    int b = blockIdx.x;
    int t = threadIdx.x;
    int c = t >> 5, d = t & 31;
    float s = 0.f;
    for (int k = 0; k < 32; ++k) s += Scp[(b * 32 + k) * 1024 + t];
    float mx = s;
    #pragma unroll
    for (int off = 16; off >= 1; off >>= 1) mx = fmaxf(mx, __shfl_xor(mx, off));
    float e = __expf(s - mx);
    float sum = e;
    #pragma unroll
    for (int off = 16; off >= 1; off >>= 1) sum += __shfl_xor(sum, off);
    pc[c * 33 + d] = e / sum;
    __syncthreads();
    // M2[o][cc] = sum_d conv6_w[o][32+d] * P[cc][d]
    int o = t >> 5, cc = t & 31;
    float m2 = 0.f;
    #pragma unroll
    for (int dd = 0; dd < 32; ++dd)
        m2 = fmaf(c6w[o * 64 + 32 + dd], pc[cc * 33 + dd], m2);
    M2[b * 1024 + o * 32 + cc] = m2;
}

// ---------------- K5: spatial attention row stats (max, sum-exp over m) ------
__global__ __launch_bounds__(256) void k_stats(
    const float* __restrict__ Q1, const float* __restrict__ K2,
    float* __restrict__ mxg, float* __restrict__ lg)
{
    __shared__ __attribute__((aligned(16))) float qs[32 * 64];
    __shared__ __attribute__((aligned(16))) float ks[32 * 64];
    __shared__ float redm[16 * 64];
    __shared__ float redl[16 * 64];
    int b = blockIdx.y;
    int n0 = blockIdx.x * 64;
    int t = threadIdx.x;
    for (int i = 0; i < 8; ++i){
        int idx = i * 256 + t; int c = idx >> 6, nl = idx & 63;
        qs[c * 64 + nl] = Q1[(b * 32 + c) * HW + n0 + nl];
    }
    int tn = t & 15, tm = t >> 4;
    float mx[4] = {-1e30f, -1e30f, -1e30f, -1e30f};
    float l[4]  = {0.f, 0.f, 0.f, 0.f};
    const float4* q4 = (const float4*)qs;
    const float4* k4 = (const float4*)ks;
    for (int mt = 0; mt < 64; ++mt){
        __syncthreads();
        for (int i = 0; i < 8; ++i){
            int idx = i * 256 + t; int c = idx >> 6, ml = idx & 63;
            ks[c * 64 + ml] = K2[(b * 32 + c) * HW + mt * 64 + ml];
        }
        __syncthreads();
        float s[4][4];
        #pragma unroll
        for (int i = 0; i < 4; ++i)
        #pragma unroll
        for (int j = 0; j < 4; ++j) s[i][j] = 0.f;
        for (int c = 0; c < 32; ++c){
            float4 q = q4[c * 16 + tn];
            float4 k = k4[c * 16 + tm];
            float qa[4] = {q.x, q.y, q.z, q.w};
            float ka[4] = {k.x, k.y, k.z, k.w};
            #pragma unroll
            for (int i = 0; i < 4; ++i)
            #pragma unroll
            for (int j = 0; j < 4; ++j) s[i][j] = fmaf(qa[i], ka[j], s[i][j]);
        }
        #pragma unroll
        for (int i = 0; i < 4; ++i){
            float vm = fmaxf(fmaxf(s[i][0], s[i][1]), fmaxf(s[i][2], s[i][3]));
            float nm = fmaxf(mx[i], vm);
            l[i] = l[i] * __expf(mx[i] - nm)
                 + __expf(s[i][0] - nm) + __expf(s[i][1] - nm)
                 + __expf(s[i][2] - nm) + __expf(s[i][3] - nm);
            mx[i] = nm;
        }
    }
    #pragma unroll
    for (int i = 0; i < 4; ++i){
        redm[tm * 64 + tn * 4 + i] = mx[i];
        redl[tm * 64 + tn * 4 + i] = l[i];
    }
    __syncthreads();
    if (t < 64){
        float M = -1e30f;
        for (int k = 0; k < 16; ++k) M = fmaxf(M, redm[k * 64 + t]);
        float L = 0.f;
        for (int k = 0; k < 16; ++k) L += redl[k * 64 + t] * __expf(redm[k * 64 + t] - M);
        mxg[b * HW + n0 + t] = M;
        lg[b * HW + n0 + t]  = L;
    }
}

// ---------------- K6: spatial attention value pass + conv6 + residual --------
__global__ __launch_bounds__(256) void k_attn(
    const float* __restrict__ Q1, const float* __restrict__ K2,
    const float* __restrict__ YQ, const float* __restrict__ YK,
    const float* __restrict__ mxg, const float* __restrict__ lg,
    const float* __restrict__ M2, const float* __restrict__ c6w,
    const float* __restrict__ c6b, const float* __restrict__ x,
    float* __restrict__ xout)
{
    __shared__ __attribute__((aligned(16))) float k2s[32 * 64];
    __shared__ __attribute__((aligned(16))) float yks[32 * 64];
    __shared__ __attribute__((aligned(16))) float q1s[32 * 64];
    __shared__ __attribute__((aligned(16))) float yqt[64 * 36];
    __shared__ __attribute__((aligned(16))) float el[64 * 68];
    __shared__ float mxs[64];
    int b = blockIdx.y;
    int m0 = blockIdx.x * 64;
    int t = threadIdx.x;
    for (int i = 0; i < 8; ++i){
        int idx = i * 256 + t; int c = idx >> 6, ml = idx & 63;
        k2s[c * 64 + ml] = K2[(b * 32 + c) * HW + m0 + ml];
        yks[c * 64 + ml] = YK[(b * 32 + c) * HW + m0 + ml];
    }
    float acc[8];
    #pragma unroll
    for (int i = 0; i < 8; ++i) acc[i] = 0.f;
    int tn = t & 15, tm = t >> 4;   // phase A indices
    int m = t & 63, cg = t >> 6;    // phase B indices
    const float4* q4 = (const float4*)q1s;
    const float4* k4 = (const float4*)k2s;
    const float4* y4 = (const float4*)yqt;

    for (int nt = 0; nt < 64; ++nt){
        int n0 = nt * 64;
        __syncthreads();   // protect q1s/yqt/el from previous iteration readers
        for (int i = 0; i < 8; ++i){
            int idx = i * 256 + t; int c = idx >> 6, nl = idx & 63;
            q1s[c * 64 + nl] = Q1[(b * 32 + c) * HW + n0 + nl];
            yqt[nl * 36 + c] = YQ[(b * 32 + c) * HW + n0 + nl] / lg[b * HW + n0 + nl];
        }
        if (t < 64) mxs[t] = mxg[b * HW + n0 + t];
        __syncthreads();

        // phase A: S tile + exp
        float s[4][4];
        #pragma unroll
        for (int i = 0; i < 4; ++i)
        #pragma unroll
        for (int j = 0; j < 4; ++j) s[i][j] = 0.f;
        for (int c = 0; c < 32; ++c){
            float4 q = q4[c * 16 + tn];
            float4 k = k4[c * 16 + tm];
            float qa[4] = {q.x, q.y, q.z, q.w};
            float ka[4] = {k.x, k.y, k.z, k.w};
            #pragma unroll
            for (int i = 0; i < 4; ++i)
            #pragma unroll
            for (int j = 0; j < 4; ++j) s[i][j] = fmaf(qa[i], ka[j], s[i][j]);
        }
        #pragma unroll
        for (int i = 0; i < 4; ++i){
            float mrow = mxs[tn * 4 + i];
            float4 e;
            e.x = __expf(s[i][0] - mrow);
            e.y = __expf(s[i][1] - mrow);
            e.z = __expf(s[i][2] - mrow);
            e.w = __expf(s[i][3] - mrow);
            *(float4*)&el[(tn * 4 + i) * 68 + tm * 4] = e;
        }
        __syncthreads();

        // phase B: acc[c] += YQt[nl][c] * E[nl][m]
        for (int nl = 0; nl < 64; ++nl){
            float e = el[nl * 68 + m];
            float4 a0 = y4[nl * 9 + cg * 2];
            float4 a1 = y4[nl * 9 + cg * 2 + 1];
            acc[0] = fmaf(a0.x, e, acc[0]);
            acc[1] = fmaf(a0.y, e, acc[1]);
            acc[2] = fmaf(a0.z, e, acc[2]);
            acc[3] = fmaf(a0.w, e, acc[3]);
            acc[4] = fmaf(a1.x, e, acc[4]);
            acc[5] = fmaf(a1.y, e, acc[5]);
            acc[6] = fmaf(a1.z, e, acc[6]);
            acc[7] = fmaf(a1.w, e, acc[7]);
        }
    }
    __syncthreads();
    // stash xy_hw tile (reuse el as [32][64])
    float* xyh = el;
    #pragma unroll
    for (int i = 0; i < 8; ++i)
        xyh[(cg * 8 + i) * 64 + m] = acc[i];
    __syncthreads();
    // epilogue: out = x + b6 + W1*xy_hw + M2*YK
    for (int i = 0; i < 8; ++i){
        int o = cg * 8 + i;
        float v = c6b[o];
        #pragma unroll
        for (int c = 0; c < 32; ++c){
            v = fmaf(c6w[o * 64 + c], xyh[c * 64 + m], v);
            v = fmaf(M2[b * 1024 + o * 32 + c], yks[c * 64 + m], v);
        }
        int gi = (b * 32 + o) * HW + m0 + m;
        xout[gi] = x[gi] + v;
    }
}

// ---------------- K7: score conv + residual on y ------------------------------
__global__ __launch_bounds__(256) void k_score(
    const float* __restrict__ xout, const float* __restrict__ y,
    const float* __restrict__ sw, const float* __restrict__ sb,
    float* __restrict__ yout)
{
    int tid = blockIdx.x * 256 + threadIdx.x;  // 0..32767
    int b = tid >> 12, pix = tid & 4095;
    int h = pix >> 6, w = pix & 63;
    bool hv[3] = {h > 0, true, h < 63};
    bool wv[3] = {w > 0, true, w < 63};
    int  hh[3] = {h - 1, h, h + 1};
    int  wwI[3] = {w - 1, w, w + 1};
    float acc = sb[0];
    const float* xb = xout + b * 32 * HW;
    for (int c = 0; c < 32; ++c){
        const float* xc = xb + c * HW;
        const float* wc = sw + c * 9;
        #pragma unroll
        for (int dy = 0; dy < 3; ++dy)
        #pragma unroll
        for (int dx = 0; dx < 3; ++dx){
            float v = (hv[dy] && wv[dx]) ? xc[hh[dy] * 64 + wwI[dx]] : 0.f;
            acc = fmaf(wc[dy * 3 + dx], v, acc);
        }
    }
    yout[tid] = y[tid] + acc;
}

extern "C" void kernel_launch(void* const* d_in, const int* in_sizes, int n_in,
                              void* d_out, int out_size, void* d_ws, size_t ws_size,
                              hipStream_t stream)
{
    (void)in_sizes; (void)n_in; (void)out_size; (void)ws_size;
    const float* x      = (const float*)d_in[0];
    const float* y      = (const float*)d_in[1];
    const float* conv_w = (const float*)d_in[2];
    const float* conv_b = (const float*)d_in[3];
    const float* score_w= (const float*)d_in[4];
    const float* score_b= (const float*)d_in[5];
    const float* c132_w = (const float*)d_in[6];
    const float* c132_b = (const float*)d_in[7];
    const float* q1w = (const float*)d_in[8];  const float* q1b = (const float*)d_in[9];
    const float* k1w = (const float*)d_in[10]; const float* k1b = (const float*)d_in[11];
    const float* q2w = (const float*)d_in[12]; const float* q2b = (const float*)d_in[13];
    const float* k2w = (const float*)d_in[14]; const float* k2b = (const float*)d_in[15];
    const float* q3w = (const float*)d_in[16]; const float* q3b = (const float*)d_in[17];
    const float* k3w = (const float*)d_in[18]; const float* k3b = (const float*)d_in[19];
    const float* c6w = (const float*)d_in[20]; const float* c6b = (const float*)d_in[21];

    float* ws = (float*)d_ws;
    const size_t SZ = 1048576;            // 8*32*4096
    float* x1 = ws;
    float* x2 = ws + SZ;
    float* Q1 = ws + 2 * SZ;
    float* K1 = ws + 3 * SZ;
    float* Q2 = ws + 4 * SZ;
    float* K2 = ws + 5 * SZ;
    float* YQ = ws + 6 * SZ;
    float* YK = ws + 7 * SZ;
    // aliases (safe: x1/x2 dead after k_proj)
    float* Scp = ws;                       // 8*32*1024 = 262144 floats
    float* M2  = ws + 262144;              // 8192 floats
    float* mxg = x2;                       // 32768 floats
    float* lg  = x2 + 32768;               // 32768 floats

    float* xout = (float*)d_out;
    float* yout = xout + SZ;

    k_front<<<dim3(16, 32, 8), 256, 0, stream>>>(x, y, conv_w, conv_b, c132_w, c132_b, x1, x2);
    k_proj<<<128, 256, 0, stream>>>(x1, x2, q1w, q1b, k1w, k1b, q2w, q2b, k2w, k2b,
                                    q3w, q3b, k3w, k3b, Q1, K1, Q2, K2, YQ, YK);
    k_chan_part<<<dim3(32, 8), 256, 0, stream>>>(K1, Q2, Scp);
    k_chan_fin<<<8, 1024, 0, stream>>>(Scp, c6w, M2);
    k_stats<<<dim3(64, 8), 256, 0, stream>>>(Q1, K2, mxg, lg);
    k_attn<<<dim3(64, 8), 256, 0, stream>>>(Q1, K2, YQ, YK, mxg, lg, M2, c6w, c6b, x, xout);
    k_score<<<128, 256, 0, stream>>>(xout, y, score_w, score_b, yout);
}

// Round 2
// 281.801 us; speedup vs baseline: 2.4636x; 2.4636x over previous
//
#include <hip/hip_runtime.h>
#include <hip/hip_bf16.h>
#include <math.h>

#define HW 4096

typedef short bf16x8_t __attribute__((ext_vector_type(8)));   // 8 bf16 (4 VGPRs)
typedef float f32x16_t __attribute__((ext_vector_type(16)));
typedef unsigned int u32;
typedef unsigned int u32x4_t __attribute__((ext_vector_type(4)));

union castu { u32x4_t u; bf16x8_t s; };

static __device__ __forceinline__ unsigned short f2bf(float f){
    union { __bf16 b; unsigned short u; } c; c.b = (__bf16)f; return c.u;
}
static __device__ __forceinline__ u32 pk2(float lo, float hi){
    return ((u32)f2bf(hi) << 16) | (u32)f2bf(lo);
}
static __device__ __forceinline__ bf16x8_t ldb(const unsigned short* p){
    return *reinterpret_cast<const bf16x8_t*>(p);
}
static __device__ __forceinline__ f32x16_t mfma32(bf16x8_t a, bf16x8_t b, f32x16_t c){
    return __builtin_amdgcn_mfma_f32_32x32x16_bf16(a, b, c, 0, 0, 0);
}

// ---------------- K1: front 3x3 convs ----------------------------------------
__global__ __launch_bounds__(256) void k_front(
    const float* __restrict__ x, const float* __restrict__ y,
    const float* __restrict__ conv_w, const float* __restrict__ conv_b,
    const float* __restrict__ c132_w, const float* __restrict__ c132_b,
    float* __restrict__ x1, float* __restrict__ x2)
{
    int pix = blockIdx.x * 256 + threadIdx.x;
    int oc = blockIdx.y;
    int b  = blockIdx.z;
    int h = pix >> 6, w = pix & 63;

    bool hv[3] = {h > 0, true, h < 63};
    bool wv[3] = {w > 0, true, w < 63};
    int  hh[3] = {h - 1, h, h + 1};
    int  wwI[3] = {w - 1, w, w + 1};

    const float* yb = y + b * HW;
    float yw[3][3];
    #pragma unroll
    for (int dy = 0; dy < 3; ++dy)
    #pragma unroll
    for (int dx = 0; dx < 3; ++dx)
        yw[dy][dx] = (hv[dy] && wv[dx]) ? yb[hh[dy] * 64 + wwI[dx]] : 0.f;

    float acc  = conv_b[oc];
    float acc2 = c132_b[oc];
    const float* wb = conv_w + oc * 40 * 9;
    const float* w2 = c132_w + oc * 9;

    #pragma unroll
    for (int t = 0; t < 9; ++t){
        float wy = 0.f;
        #pragma unroll
        for (int g = 0; g < 8; ++g) wy += wb[(5 * g + 4) * 9 + t];
        float yv = yw[t / 3][t % 3];
        acc  += wy * yv;
        acc2 += w2[t] * yv;
    }

    const float* xb = x + b * 32 * HW;
    for (int ic = 0; ic < 32; ++ic){
        const float* xc = xb + ic * HW;
        const float* wc = wb + (5 * (ic >> 2) + (ic & 3)) * 9;
        #pragma unroll
        for (int dy = 0; dy < 3; ++dy)
        #pragma unroll
        for (int dx = 0; dx < 3; ++dx){
            float xv = (hv[dy] && wv[dx]) ? xc[hh[dy] * 64 + wwI[dx]] : 0.f;
            acc = fmaf(wc[dy * 3 + dx], xv, acc);
        }
    }
    int o = (b * 32 + oc) * HW + pix;
    x1[o] = acc > 0.f ? acc : 0.f;
    x2[o] = acc2;
}

// ---------------- K2: six 1x1 projections ------------------------------------
__global__ __launch_bounds__(256) void k_proj(
    const float* __restrict__ x1, const float* __restrict__ x2,
    const float* __restrict__ q1w, const float* __restrict__ q1b,
    const float* __restrict__ k1w, const float* __restrict__ k1b,
    const float* __restrict__ q2w, const float* __restrict__ q2b,
    const float* __restrict__ k2w, const float* __restrict__ k2b,
    const float* __restrict__ q3w, const float* __restrict__ q3b,
    const float* __restrict__ k3w, const float* __restrict__ k3b,
    float* __restrict__ K1, float* __restrict__ Q2, float* __restrict__ YQ,
    unsigned short* __restrict__ Q1t, unsigned short* __restrict__ K2t,
    unsigned short* __restrict__ YKt)
{
    int tid = blockIdx.x * 256 + threadIdx.x;   // 0..32767
    int b = tid >> 12, m = tid & 4095;
    float v1[32], v2[32];
    const float* p1 = x1 + b * 32 * HW + m;
    const float* p2 = x2 + b * 32 * HW + m;
    #pragma unroll
    for (int c = 0; c < 32; ++c){ v1[c] = p1[c * HW]; v2[c] = p2[c * HW]; }

    unsigned short* q1p = Q1t + (size_t)tid * 32;
    unsigned short* k2p = K2t + (size_t)tid * 32;
    unsigned short* ykp = YKt + (size_t)tid * 32;

    for (int oc = 0; oc < 32; ++oc){
        float aq1 = q1b[oc], ak1 = k1b[oc], aq2 = q2b[oc];
        float ak2 = k2b[oc], aq3 = q3b[oc], ak3 = k3b[oc];
        #pragma unroll
        for (int c = 0; c < 32; ++c){
            float v = v1[c], u = v2[c];
            aq1 = fmaf(q1w[oc * 32 + c], v, aq1);
            ak1 = fmaf(k1w[oc * 32 + c], v, ak1);
            aq2 = fmaf(q2w[oc * 32 + c], v, aq2);
            ak2 = fmaf(k2w[oc * 32 + c], v, ak2);
            aq3 = fmaf(q3w[oc * 32 + c], u, aq3);
            ak3 = fmaf(k3w[oc * 32 + c], u, ak3);
        }
        int o = (b * 32 + oc) * HW + m;
        K1[o] = ak1; Q2[o] = aq2; YQ[o] = aq3;
        q1p[oc] = f2bf(aq1);
        k2p[oc] = f2bf(ak2);
        ykp[oc] = f2bf(ak3);
    }
}

// ---------------- K3: channel attention partial sums -------------------------
__global__ __launch_bounds__(256) void k_chan_part(
    const float* __restrict__ K1, const float* __restrict__ Q2,
    float* __restrict__ Scp)
{
    __shared__ float k1s[128 * 33];
    __shared__ float q2s[128 * 33];
    int chunk = blockIdx.x;     // 0..31, 128 n each
    int b = blockIdx.y;
    int n0 = chunk * 128;
    int t = threadIdx.x;
    for (int i = 0; i < 16; ++i){
        int idx = i * 256 + t;
        int c = idx >> 7, nl = idx & 127;
        k1s[nl * 33 + c] = K1[(b * 32 + c) * HW + n0 + nl];
        q2s[nl * 33 + c] = Q2[(b * 32 + c) * HW + n0 + nl];
    }
    __syncthreads();
    float acc[4] = {0.f, 0.f, 0.f, 0.f};
    int d = t & 31, c0 = t >> 5;
    for (int nl = 0; nl < 128; ++nl){
        float qv = q2s[nl * 33 + d];
        #pragma unroll
        for (int i = 0; i < 4; ++i)
            acc[i] = fmaf(k1s[nl * 33 + c0 + 8 * i], qv, acc[i]);
    }
    #pragma unroll
    for (int i = 0; i < 4; ++i)
        Scp[(b * 32 + chunk) * 1024 + (c0 + 8 * i) * 32 + d] = acc[i];
}

// ---------------- K4: channel softmax + fold conv6 W2 into M2 ----------------
__global__ __launch_bounds__(1024) void k_chan_fin(
    const float* __restrict__ Scp, const float* __restrict__ c6w,
    float* __restrict__ M2)
{
    __shared__ float pc[32 * 33];
    int b = blockIdx.x;
    int t = threadIdx.x;
    int c = t >> 5, d = t & 31;
    float s = 0.f;
    for (int k = 0; k < 32; ++k) s += Scp[(b * 32 + k) * 1024 + t];
    float mx = s;
    #pragma unroll
    for (int off = 16; off >= 1; off >>= 1) mx = fmaxf(mx, __shfl_xor(mx, off));
    float e = __expf(s - mx);
    float sum = e;
    #pragma unroll
    for (int off = 16; off >= 1; off >>= 1) sum += __shfl_xor(sum, off);
    pc[c * 33 + d] = e / sum;
    __syncthreads();
    int o = t >> 5, cc = t & 31;
    float m2 = 0.f;
    #pragma unroll
    for (int dd = 0; dd < 32; ++dd)
        m2 = fmaf(c6w[o * 64 + 32 + dd], pc[cc * 33 + dd], m2);
    M2[b * 1024 + o * 32 + cc] = m2;
}

// ---------------- K5: MFMA stats pass: l[n] = sum_m exp(S[n,m]) --------------
__global__ __launch_bounds__(256) void k_stats_mfma(
    const unsigned short* __restrict__ Q1t, const unsigned short* __restrict__ K2t,
    float* __restrict__ lsum)
{
    __shared__ float red[4][16][64];
    int t = threadIdx.x, wid = t >> 6, lane = t & 63;
    int l31 = lane & 31, h = lane >> 5;
    int b = blockIdx.x >> 7, ntile = blockIdx.x & 127;
    int n0 = ntile * 32;
    const unsigned short* q = Q1t + (size_t)b * 131072;
    const unsigned short* k = K2t + (size_t)b * 131072;
    // A-frags (fixed): A[row n][k c]; row = lane&31, k = 8*(lane>>5)+i
    bf16x8_t a0 = ldb(q + (size_t)(n0 + l31) * 32 + 8 * h);
    bf16x8_t a1 = ldb(q + (size_t)(n0 + l31) * 32 + 16 + 8 * h);
    float accl[16];
    #pragma unroll
    for (int r = 0; r < 16; ++r) accl[r] = 0.f;
    for (int mt = wid * 32; mt < wid * 32 + 32; ++mt){
        const unsigned short* kp = k + ((size_t)mt * 32 + l31) * 32 + 8 * h;
        bf16x8_t b0 = ldb(kp);
        bf16x8_t b1 = ldb(kp + 16);
        f32x16_t s;
        #pragma unroll
        for (int r = 0; r < 16; ++r) s[r] = 0.f;
        s = mfma32(a0, b0, s);
        s = mfma32(a1, b1, s);
        #pragma unroll
        for (int r = 0; r < 16; ++r) accl[r] += __expf(s[r]);
    }
    #pragma unroll
    for (int r = 0; r < 16; ++r) red[wid][r][lane] = accl[r];
    __syncthreads();
    if (wid != 0) return;
    #pragma unroll
    for (int r = 0; r < 16; ++r){
        float v = red[0][r][lane] + red[1][r][lane] + red[2][r][lane] + red[3][r][lane];
        #pragma unroll
        for (int off = 16; off >= 1; off >>= 1) v += __shfl_xor(v, off);
        if (l31 == 0)
            lsum[b * HW + n0 + (r & 3) + 8 * (r >> 2) + 4 * h] = v;
    }
}

// ---------------- K6: scale YQ by 1/l, emit bf16 ------------------------------
__global__ __launch_bounds__(256) void k_scale(
    const float* __restrict__ YQ, const float* __restrict__ lsum,
    unsigned short* __restrict__ YQ2)
{
    int tid = blockIdx.x * 256 + threadIdx.x;     // 0..262143
    int base = tid * 4;
    int b = base >> 17;
    int n = base & 4095;
    const float4 yq = *(const float4*)(YQ + base);
    const float4 lv = *(const float4*)(lsum + b * HW + n);
    u32 lo = pk2(yq.x / lv.x, yq.y / lv.y);
    u32 hi = pk2(yq.z / lv.z, yq.w / lv.w);
    *(uint2*)(YQ2 + base) = make_uint2(lo, hi);
}

// ---------------- K7: MFMA value pass + conv6 + residual ----------------------
__global__ __launch_bounds__(256) void k_attn_mfma(
    const unsigned short* __restrict__ Q1t, const unsigned short* __restrict__ K2t,
    const unsigned short* __restrict__ YKt, const unsigned short* __restrict__ YQ2,
    const float* __restrict__ M2, const float* __restrict__ c6w, const float* __restrict__ c6b,
    const float* __restrict__ x, float* __restrict__ xout)
{
    __shared__ float red[4][16][64];
    int t = threadIdx.x, wid = t >> 6, lane = t & 63;
    int l31 = lane & 31, h = lane >> 5;
    int b = blockIdx.x >> 7, mtile = blockIdx.x & 127;
    int m0 = mtile * 32;
    size_t boff = (size_t)b * 131072;
    const unsigned short* qb = Q1t + boff;
    const unsigned short* kb = K2t + boff;
    const unsigned short* yqb = YQ2 + boff;

    // S B-frags (fixed per wave): B[k c][col m]; col = lane&31
    bf16x8_t kb0 = ldb(kb + (size_t)(m0 + l31) * 32 + 8 * h);
    bf16x8_t kb1 = ldb(kb + (size_t)(m0 + l31) * 32 + 16 + 8 * h);

    f32x16_t oacc;
    #pragma unroll
    for (int r = 0; r < 16; ++r) oacc[r] = 0.f;

    const unsigned short* yq_base = yqb + (size_t)l31 * HW + 8 * h;

    for (int nt = wid * 32; nt < wid * 32 + 32; ++nt){
        int n0 = nt * 32;
        // S A-frags: A[row n][k c]
        bf16x8_t a0 = ldb(qb + (size_t)(n0 + l31) * 32 + 8 * h);
        bf16x8_t a1 = ldb(qb + (size_t)(n0 + l31) * 32 + 16 + 8 * h);
        f32x16_t s;
        #pragma unroll
        for (int r = 0; r < 16; ++r) s[r] = 0.f;
        s = mfma32(a0, kb0, s);
        s = mfma32(a1, kb1, s);
        // E = exp(S); convert C/D layout -> B-frag layout (k = n)
        u32 P[8];
        #pragma unroll
        for (int tt = 0; tt < 8; ++tt)
            P[tt] = pk2(__expf(s[2 * tt]), __expf(s[2 * tt + 1]));
        u32 X[8];
        #pragma unroll
        for (int tt = 0; tt < 8; ++tt) X[tt] = (u32)__shfl_xor((int)P[tt], 32);
        castu e0, e1;
        e0.u = (u32x4_t){ h ? X[2] : P[0], h ? X[3] : P[1], h ? P[2] : X[0], h ? P[3] : X[1] };
        e1.u = (u32x4_t){ h ? X[6] : P[4], h ? X[7] : P[5], h ? P[6] : X[4], h ? P[7] : X[5] };
        // PV: out[c][m] += YQ2[c][n-chunk] * E[n-chunk][m]
        bf16x8_t ya0 = ldb(yq_base + n0);
        bf16x8_t ya1 = ldb(yq_base + n0 + 16);
        oacc = mfma32(ya0, e0.s, oacc);
        oacc = mfma32(ya1, e1.s, oacc);
    }
    #pragma unroll
    for (int r = 0; r < 16; ++r) red[wid][r][lane] = oacc[r];
    __syncthreads();
    if (wid != 0) return;
    #pragma unroll
    for (int r = 0; r < 16; ++r)
        oacc[r] = red[0][r][lane] + red[1][r][lane] + red[2][r][lane] + red[3][r][lane];

    // oacc = xy_hw[c rows(regs)][m cols(lanes)] -> B-frags (k = c)
    u32 P[8], X[8];
    #pragma unroll
    for (int tt = 0; tt < 8; ++tt) P[tt] = pk2(oacc[2 * tt], oacc[2 * tt + 1]);
    #pragma unroll
    for (int tt = 0; tt < 8; ++tt) X[tt] = (u32)__shfl_xor((int)P[tt], 32);
    castu xb0, xb1;
    xb0.u = (u32x4_t){ h ? X[2] : P[0], h ? X[3] : P[1], h ? P[2] : X[0], h ? P[3] : X[1] };
    xb1.u = (u32x4_t){ h ? X[6] : P[4], h ? X[7] : P[5], h ? P[6] : X[4], h ? P[7] : X[5] };

    // W1 A-frags: rows o = lane&31, k = c
    const float* w1p = c6w + l31 * 64;
    const float* m2p = M2 + b * 1024 + l31 * 32;
    int cb0 = 8 * h, cb1 = 16 + 8 * h;
    castu wa0, wa1, ma0, ma1;
    wa0.u = (u32x4_t){ pk2(w1p[cb0], w1p[cb0+1]), pk2(w1p[cb0+2], w1p[cb0+3]),
                       pk2(w1p[cb0+4], w1p[cb0+5]), pk2(w1p[cb0+6], w1p[cb0+7]) };
    wa1.u = (u32x4_t){ pk2(w1p[cb1], w1p[cb1+1]), pk2(w1p[cb1+2], w1p[cb1+3]),
                       pk2(w1p[cb1+4], w1p[cb1+5]), pk2(w1p[cb1+6], w1p[cb1+7]) };
    ma0.u = (u32x4_t){ pk2(m2p[cb0], m2p[cb0+1]), pk2(m2p[cb0+2], m2p[cb0+3]),
                       pk2(m2p[cb0+4], m2p[cb0+5]), pk2(m2p[cb0+6], m2p[cb0+7]) };
    ma1.u = (u32x4_t){ pk2(m2p[cb1], m2p[cb1+1]), pk2(m2p[cb1+2], m2p[cb1+3]),
                       pk2(m2p[cb1+4], m2p[cb1+5]), pk2(m2p[cb1+6], m2p[cb1+7]) };
    // YK B-frags: col m = lane&31, k = c
    const unsigned short* ykp = YKt + boff + (size_t)(m0 + l31) * 32;
    bf16x8_t ykb0 = ldb(ykp + 8 * h);
    bf16x8_t ykb1 = ldb(ykp + 16 + 8 * h);

    f32x16_t facc;
    #pragma unroll
    for (int r = 0; r < 16; ++r) facc[r] = c6b[(r & 3) + 8 * (r >> 2) + 4 * h];
    facc = mfma32(wa0.s, xb0.s, facc);
    facc = mfma32(wa1.s, xb1.s, facc);
    facc = mfma32(ma0.s, ykb0, facc);
    facc = mfma32(ma1.s, ykb1, facc);

    #pragma unroll
    for (int r = 0; r < 16; ++r){
        int o = (r & 3) + 8 * (r >> 2) + 4 * h;
        size_t gi = ((size_t)(b * 32 + o) << 12) + m0 + l31;
        xout[gi] = x[gi] + facc[r];
    }
}

// ---------------- K8: score conv + residual on y ------------------------------
__global__ __launch_bounds__(256) void k_score(
    const float* __restrict__ xout, const float* __restrict__ y,
    const float* __restrict__ sw, const float* __restrict__ sb,
    float* __restrict__ yout)
{
    int tid = blockIdx.x * 256 + threadIdx.x;  // 0..32767
    int b = tid >> 12, pix = tid & 4095;
    int h = pix >> 6, w = pix & 63;
    bool hv[3] = {h > 0, true, h < 63};
    bool wv[3] = {w > 0, true, w < 63};
    int  hh[3] = {h - 1, h, h + 1};
    int  wwI[3] = {w - 1, w, w + 1};
    float acc = sb[0];
    const float* xb = xout + b * 32 * HW;
    for (int c = 0; c < 32; ++c){
        const float* xc = xb + c * HW;
        const float* wc = sw + c * 9;
        #pragma unroll
        for (int dy = 0; dy < 3; ++dy)
        #pragma unroll
        for (int dx = 0; dx < 3; ++dx){
            float v = (hv[dy] && wv[dx]) ? xc[hh[dy] * 64 + wwI[dx]] : 0.f;
            acc = fmaf(wc[dy * 3 + dx], v, acc);
        }
    }
    yout[tid] = y[tid] + acc;
}

extern "C" void kernel_launch(void* const* d_in, const int* in_sizes, int n_in,
                              void* d_out, int out_size, void* d_ws, size_t ws_size,
                              hipStream_t stream)
{
    (void)in_sizes; (void)n_in; (void)out_size; (void)ws_size;
    const float* x      = (const float*)d_in[0];
    const float* y      = (const float*)d_in[1];
    const float* conv_w = (const float*)d_in[2];
    const float* conv_b = (const float*)d_in[3];
    const float* score_w= (const float*)d_in[4];
    const float* score_b= (const float*)d_in[5];
    const float* c132_w = (const float*)d_in[6];
    const float* c132_b = (const float*)d_in[7];
    const float* q1w = (const float*)d_in[8];  const float* q1b = (const float*)d_in[9];
    const float* k1w = (const float*)d_in[10]; const float* k1b = (const float*)d_in[11];
    const float* q2w = (const float*)d_in[12]; const float* q2b = (const float*)d_in[13];
    const float* k2w = (const float*)d_in[14]; const float* k2b = (const float*)d_in[15];
    const float* q3w = (const float*)d_in[16]; const float* q3b = (const float*)d_in[17];
    const float* k3w = (const float*)d_in[18]; const float* k3b = (const float*)d_in[19];
    const float* c6w = (const float*)d_in[20]; const float* c6b = (const float*)d_in[21];

    float* ws = (float*)d_ws;
    const size_t SZ = 1048576;            // 8*32*4096
    float* x1  = ws;                      // 1M f32
    float* x2  = ws + SZ;                 // 1M f32
    float* K1  = ws + 2 * SZ;             // 1M f32
    float* Q2  = ws + 3 * SZ;             // 1M f32
    float* YQf = ws + 4 * SZ;             // 1M f32
    unsigned short* Q1t = (unsigned short*)(ws + 5 * SZ);            // 1M bf16
    unsigned short* K2t = (unsigned short*)(ws + 5 * SZ + SZ / 2);   // 1M bf16
    unsigned short* YKt = (unsigned short*)(ws + 6 * SZ);            // 1M bf16
    unsigned short* YQ2 = (unsigned short*)(ws + 6 * SZ + SZ / 2);   // 1M bf16
    float* lsum = ws + 7 * SZ;            // 32768 f32
    // aliases (x1 dead after k_proj)
    float* Scp = x1;                      // 262144 f32
    float* M2  = x1 + 262144;             // 8192 f32

    float* xout = (float*)d_out;
    float* yout = xout + SZ;

    k_front<<<dim3(16, 32, 8), 256, 0, stream>>>(x, y, conv_w, conv_b, c132_w, c132_b, x1, x2);
    k_proj<<<128, 256, 0, stream>>>(x1, x2, q1w, q1b, k1w, k1b, q2w, q2b, k2w, k2b,
                                    q3w, q3b, k3w, k3b, K1, Q2, YQf, Q1t, K2t, YKt);
    k_chan_part<<<dim3(32, 8), 256, 0, stream>>>(K1, Q2, Scp);
    k_chan_fin<<<8, 1024, 0, stream>>>(Scp, c6w, M2);
    k_stats_mfma<<<1024, 256, 0, stream>>>(Q1t, K2t, lsum);
    k_scale<<<1024, 256, 0, stream>>>(YQf, lsum, YQ2);
    k_attn_mfma<<<1024, 256, 0, stream>>>(Q1t, K2t, YKt, YQ2, M2, c6w, c6b, x, xout);
    k_score<<<128, 256, 0, stream>>>(xout, y, score_w, score_b, yout);
}